// Round 1
// baseline (100.033 us; speedup 1.0000x reference)
//
#include <hip/hip_runtime.h>
#include <hip/hip_bf16.h>

typedef __attribute__((ext_vector_type(8))) short bf16x8;
typedef __attribute__((ext_vector_type(4))) float f32x4;

#define GRU_B 131072
#define BM 64

static __device__ __forceinline__ ushort f2bf(float f) {
  union { float f; unsigned u; } v; v.f = f;
  unsigned r = v.u + 0x7FFFu + ((v.u >> 16) & 1u);   // RNE
  return (ushort)(r >> 16);
}
static __device__ __forceinline__ float bf2f(ushort u) {
  union { unsigned u; float f; } v; v.u = ((unsigned)u) << 16;
  return v.f;
}
static __device__ __forceinline__ float fsig(float x) {
  return __builtin_amdgcn_rcpf(1.0f + __expf(-x));
}
static __device__ __forceinline__ float ftanh(float x) {
  // tanh(x) = 1 - 2/(exp(2x)+1); exp->inf / ->0 give correct +-1 saturation
  return 1.0f - 2.0f * __builtin_amdgcn_rcpf(1.0f + __expf(2.0f * x));
}

// Transpose + cast the six 128x128 fp32 weight matrices into bf16 W^T rows:
// ws layout: [mat][n][k] bf16, mat in {Wz,Uz,Wr,Ur,Wh,Uh}. 98304 elements.
__global__ void wtrans_kernel(const float* __restrict__ wz, const float* __restrict__ uz,
                              const float* __restrict__ wr, const float* __restrict__ ur,
                              const float* __restrict__ wh, const float* __restrict__ uh,
                              ushort* __restrict__ outw) {
  int f = blockIdx.x * 256 + threadIdx.x;          // 0..98303
  int mat = f >> 14;
  int r = f & 16383;                               // source-linear: k*128+n (coalesced read)
  const float* src = (mat == 0) ? wz : (mat == 1) ? uz : (mat == 2) ? wr
                   : (mat == 3) ? ur : (mat == 4) ? wh : uh;
  outw[(mat << 14) + ((r & 127) << 7) + (r >> 7)] = f2bf(src[r]);
}

__global__ __launch_bounds__(256, 3) void gru_kernel(
    const float* __restrict__ x, const float* __restrict__ hprev,
    const ushort* __restrict__ wt,
    const float* __restrict__ bz, const float* __restrict__ br,
    const float* __restrict__ bh, float* __restrict__ out) {
  __shared__ ushort xs[BM * 128];   // bf16, XOR-swizzled rows (256 B/row)
  __shared__ ushort hs[BM * 128];
  __shared__ ushort rhs[BM * 128];  // r * h_prev, bf16, same layout

  const int tid = threadIdx.x;
  const int lane = tid & 63;
  const int wid = tid >> 6;          // 4 waves: column partition
  const int l15 = lane & 15;
  const int q = lane >> 4;           // quarter-wave 0..3
  const long row0 = (long)blockIdx.x * BM;
  const int n0 = wid * 32;           // this wave's 32 hidden columns

  // ---------------- stage x, h -> LDS bf16 (swizzled) ----------------
  {
    const float4* xg = (const float4*)(x + row0 * 128);
    const float4* hg = (const float4*)(hprev + row0 * 128);
#pragma unroll
    for (int i = 0; i < 8; ++i) {
      int idx = i * 256 + tid;        // float4 index, 0..2047
      int r = idx >> 5;               // row 0..63
      int cb = (idx & 31) << 3;       // byte-in-row of first col (col*2)
      int bo = (r * 256 + cb) ^ ((r & 7) << 4);
      float4 xv = xg[idx];
      float4 hv = hg[idx];
      uint2 xp, hp;
      xp.x = (unsigned)f2bf(xv.x) | ((unsigned)f2bf(xv.y) << 16);
      xp.y = (unsigned)f2bf(xv.z) | ((unsigned)f2bf(xv.w) << 16);
      hp.x = (unsigned)f2bf(hv.x) | ((unsigned)f2bf(hv.y) << 16);
      hp.y = (unsigned)f2bf(hv.z) | ((unsigned)f2bf(hv.w) << 16);
      *(uint2*)((char*)xs + bo) = xp;
      *(uint2*)((char*)hs + bo) = hp;
    }
  }
  __syncthreads();

  const ushort* wzt = wt;
  const ushort* uzt = wt + (1 << 14);
  const ushort* wrt = wt + (2 << 14);
  const ushort* urt = wt + (3 << 14);
  const ushort* wht = wt + (4 << 14);
  const ushort* uht = wt + (5 << 14);

  auto ldsA = [&](const ushort* base, int mr, int kb) -> bf16x8 {
    int row = mr * 16 + l15;
    int bo = (row * 256 + kb * 2) ^ ((row & 7) << 4);
    return *(const bf16x8*)((const char*)base + bo);
  };
  auto ldgB = [&](const ushort* w, int nc, int kb) -> bf16x8 {
    return *(const bf16x8*)(w + ((n0 + nc * 16 + l15) << 7) + kb);
  };

  // ---------------- z gate: sigmoid(x@Wz + h@Uz + bz) ----------------
  f32x4 accz[4][2];
#pragma unroll
  for (int mr = 0; mr < 4; ++mr) { accz[mr][0] = (f32x4)0.0f; accz[mr][1] = (f32x4)0.0f; }
  for (int k0 = 0; k0 < 128; k0 += 32) {
    int kb = k0 + q * 8;
    bf16x8 b0 = ldgB(wzt, 0, kb), b1 = ldgB(wzt, 1, kb);
    bf16x8 c0 = ldgB(uzt, 0, kb), c1 = ldgB(uzt, 1, kb);
#pragma unroll
    for (int mr = 0; mr < 4; ++mr) {
      bf16x8 ax = ldsA(xs, mr, kb);
      bf16x8 ah = ldsA(hs, mr, kb);
      accz[mr][0] = __builtin_amdgcn_mfma_f32_16x16x32_bf16(ax, b0, accz[mr][0], 0, 0, 0);
      accz[mr][1] = __builtin_amdgcn_mfma_f32_16x16x32_bf16(ax, b1, accz[mr][1], 0, 0, 0);
      accz[mr][0] = __builtin_amdgcn_mfma_f32_16x16x32_bf16(ah, c0, accz[mr][0], 0, 0, 0);
      accz[mr][1] = __builtin_amdgcn_mfma_f32_16x16x32_bf16(ah, c1, accz[mr][1], 0, 0, 0);
    }
  }
  {
    float bv0 = bz[n0 + l15], bv1 = bz[n0 + 16 + l15];
#pragma unroll
    for (int mr = 0; mr < 4; ++mr)
#pragma unroll
      for (int j = 0; j < 4; ++j) {
        accz[mr][0][j] = fsig(accz[mr][0][j] + bv0);
        accz[mr][1][j] = fsig(accz[mr][1][j] + bv1);
      }
  }

  // ---------------- r gate + rh = r*h_prev -> LDS ----------------
  {
    f32x4 accr[4][2];
#pragma unroll
    for (int mr = 0; mr < 4; ++mr) { accr[mr][0] = (f32x4)0.0f; accr[mr][1] = (f32x4)0.0f; }
    for (int k0 = 0; k0 < 128; k0 += 32) {
      int kb = k0 + q * 8;
      bf16x8 b0 = ldgB(wrt, 0, kb), b1 = ldgB(wrt, 1, kb);
      bf16x8 c0 = ldgB(urt, 0, kb), c1 = ldgB(urt, 1, kb);
#pragma unroll
      for (int mr = 0; mr < 4; ++mr) {
        bf16x8 ax = ldsA(xs, mr, kb);
        bf16x8 ah = ldsA(hs, mr, kb);
        accr[mr][0] = __builtin_amdgcn_mfma_f32_16x16x32_bf16(ax, b0, accr[mr][0], 0, 0, 0);
        accr[mr][1] = __builtin_amdgcn_mfma_f32_16x16x32_bf16(ax, b1, accr[mr][1], 0, 0, 0);
        accr[mr][0] = __builtin_amdgcn_mfma_f32_16x16x32_bf16(ah, c0, accr[mr][0], 0, 0, 0);
        accr[mr][1] = __builtin_amdgcn_mfma_f32_16x16x32_bf16(ah, c1, accr[mr][1], 0, 0, 0);
      }
    }
    float bv0 = br[n0 + l15], bv1 = br[n0 + 16 + l15];
#pragma unroll
    for (int mr = 0; mr < 4; ++mr)
#pragma unroll
      for (int nc = 0; nc < 2; ++nc)
#pragma unroll
        for (int j = 0; j < 4; ++j) {
          int row = mr * 16 + q * 4 + j;
          int col = n0 + nc * 16 + l15;
          float rv = fsig(accr[mr][nc][j] + (nc ? bv1 : bv0));
          int bo = (row * 256 + col * 2) ^ ((row & 7) << 4);
          float hp = bf2f(*(const ushort*)((const char*)hs + bo));
          *(ushort*)((char*)rhs + bo) = f2bf(rv * hp);
        }
  }

  // ---------------- xwh = x@Wh ----------------
  f32x4 acch[4][2];
#pragma unroll
  for (int mr = 0; mr < 4; ++mr) { acch[mr][0] = (f32x4)0.0f; acch[mr][1] = (f32x4)0.0f; }
  for (int k0 = 0; k0 < 128; k0 += 32) {
    int kb = k0 + q * 8;
    bf16x8 b0 = ldgB(wht, 0, kb), b1 = ldgB(wht, 1, kb);
#pragma unroll
    for (int mr = 0; mr < 4; ++mr) {
      bf16x8 ax = ldsA(xs, mr, kb);
      acch[mr][0] = __builtin_amdgcn_mfma_f32_16x16x32_bf16(ax, b0, acch[mr][0], 0, 0, 0);
      acch[mr][1] = __builtin_amdgcn_mfma_f32_16x16x32_bf16(ax, b1, acch[mr][1], 0, 0, 0);
    }
  }

  __syncthreads();   // all waves finished writing rhs

  // ---------------- += (r*h)@Uh ----------------
  for (int k0 = 0; k0 < 128; k0 += 32) {
    int kb = k0 + q * 8;
    bf16x8 b0 = ldgB(uht, 0, kb), b1 = ldgB(uht, 1, kb);
#pragma unroll
    for (int mr = 0; mr < 4; ++mr) {
      bf16x8 ar = ldsA(rhs, mr, kb);
      acch[mr][0] = __builtin_amdgcn_mfma_f32_16x16x32_bf16(ar, b0, acch[mr][0], 0, 0, 0);
      acch[mr][1] = __builtin_amdgcn_mfma_f32_16x16x32_bf16(ar, b1, acch[mr][1], 0, 0, 0);
    }
  }

  // ---------------- epilogue: h_t = (1-z)*h + z*tanh(acch+bh) ----------------
  {
    float bv0 = bh[n0 + l15], bv1 = bh[n0 + 16 + l15];
#pragma unroll
    for (int mr = 0; mr < 4; ++mr)
#pragma unroll
      for (int nc = 0; nc < 2; ++nc)
#pragma unroll
        for (int j = 0; j < 4; ++j) {
          int row = mr * 16 + q * 4 + j;
          int col = n0 + nc * 16 + l15;
          float hc = ftanh(acch[mr][nc][j] + (nc ? bv1 : bv0));
          float zv = accz[mr][nc][j];
          int bo = (row * 256 + col * 2) ^ ((row & 7) << 4);
          float hp = bf2f(*(const ushort*)((const char*)hs + bo));
          out[(row0 + row) * 128 + col] = (1.0f - zv) * hp + zv * hc;
        }
  }
}

extern "C" void kernel_launch(void* const* d_in, const int* in_sizes, int n_in,
                              void* d_out, int out_size, void* d_ws, size_t ws_size,
                              hipStream_t stream) {
  const float* x  = (const float*)d_in[0];
  const float* h  = (const float*)d_in[1];
  const float* Wz = (const float*)d_in[2];
  const float* Uz = (const float*)d_in[3];
  const float* bz = (const float*)d_in[4];
  const float* Wr = (const float*)d_in[5];
  const float* Ur = (const float*)d_in[6];
  const float* br = (const float*)d_in[7];
  const float* Wh = (const float*)d_in[8];
  const float* Uh = (const float*)d_in[9];
  const float* bh = (const float*)d_in[10];
  ushort* wt = (ushort*)d_ws;   // 98304 bf16 = 192 KB

  hipLaunchKernelGGL(wtrans_kernel, dim3(384), dim3(256), 0, stream,
                     Wz, Uz, Wr, Ur, Wh, Uh, wt);
  hipLaunchKernelGGL(gru_kernel, dim3(GRU_B / BM), dim3(256), 0, stream,
                     x, h, wt, bz, br, bh, (float*)d_out);
}